// Round 3
// baseline (13663.736 us; speedup 1.0000x reference)
//
#include <hip/hip_runtime.h>
#include <hip/hip_cooperative_groups.h>

namespace cg = cooperative_groups;

#define V_ 32000
#define E_ 256
#define U_ 512
#define B_ 64
#define T_ 256
#define G_ 2048      // 4*U
#define KTOT 768     // E + U
#define WSTRIDE 772  // 768 + 4 pad (bank-conflict break, keeps 16B alignment)

// grid: 256 blocks x 512 threads, persistent cooperative kernel.
// block -> (dir, b-half of 32, u-slice of 8) ; weights for its 32 gate-cols live in LDS.
__global__ __launch_bounds__(512, 1)
void bilstm_kernel(const int* __restrict__ x,
                   const float* __restrict__ emb,
                   const float* __restrict__ Wf, const float* __restrict__ Rf,
                   const float* __restrict__ bf,
                   const float* __restrict__ Wb, const float* __restrict__ Rb,
                   const float* __restrict__ bb,
                   float* __restrict__ out, float* __restrict__ hbuf)
{
    __shared__ float Wl[32 * WSTRIDE];   // 98816 B, transposed weights [gc][k]
    __shared__ float zx[32 * 32];        // z exchange [gc][b_loc]
    __shared__ float cst[256];           // c state   [b_loc*8 + uu]

    const int blk = blockIdx.x;
    const int dir = blk >> 7;            // 0 fwd, 1 bwd
    const int rem = blk & 127;
    const int u0 = (rem >> 1) * 8;       // u-slice base
    const int b0base = (rem & 1) * 32;   // batch half

    const int tid = threadIdx.x;
    const int gc  = tid & 31;            // gate-col within block (0..31)
    const int bp  = tid >> 5;            // batch pair (0..15)
    const int gate = gc >> 3;
    const int uu   = gc & 7;
    const int g    = gate * 512 + u0 + uu;   // global gate column

    const float* Wd = dir ? Wb : Wf;
    const float* Rd = dir ? Rb : Rf;
    const float* bd = dir ? bb : bf;

    // ---- one-time: stage this block's 32 weight columns into LDS, transposed ----
    for (int k = bp; k < KTOT; k += 16) {
        float v = (k < E_) ? Wd[(size_t)k * G_ + g]
                           : Rd[(size_t)(k - E_) * G_ + g];
        Wl[gc * WSTRIDE + k] = v;
    }
    if (tid < 256) cst[tid] = 0.0f;

    // zero h double-buffer slot 0 (2 dirs x 64 x 512 = 65536 floats)
    {
        int idx = blk * 512 + tid;
        if (idx < 2 * B_ * U_) hbuf[idx] = 0.0f;
    }

    const float bias_g = bd[g];
    const int bg0 = b0base + bp * 2;
    const int bg1 = bg0 + 1;

    cg::grid_group grid = cg::this_grid();
    grid.sync();

    const float4* WlA = reinterpret_cast<const float4*>(&Wl[gc * WSTRIDE]);

    for (int s = 0; s < T_; ++s) {
        const int te  = dir ? (T_ - 1 - s) : s;
        const int cur = s & 1;
        const int nxt = cur ^ 1;

        float acc0 = bias_g, acc1 = bias_g;

        // ---- x-projection part: emb[x[b,te]] @ W  (K = 0..255) ----
        const float4* e0 = reinterpret_cast<const float4*>(
            emb + (size_t)x[bg0 * T_ + te] * E_);
        const float4* e1 = reinterpret_cast<const float4*>(
            emb + (size_t)x[bg1 * T_ + te] * E_);
        #pragma unroll 8
        for (int k4 = 0; k4 < E_ / 4; ++k4) {
            float4 w = WlA[k4];
            float4 a = e0[k4];
            float4 c = e1[k4];
            acc0 = fmaf(w.x, a.x, acc0); acc0 = fmaf(w.y, a.y, acc0);
            acc0 = fmaf(w.z, a.z, acc0); acc0 = fmaf(w.w, a.w, acc0);
            acc1 = fmaf(w.x, c.x, acc1); acc1 = fmaf(w.y, c.y, acc1);
            acc1 = fmaf(w.z, c.z, acc1); acc1 = fmaf(w.w, c.w, acc1);
        }

        // ---- recurrent part: h @ R  (K = 256..767) ----
        const float4* h0 = reinterpret_cast<const float4*>(
            hbuf + ((size_t)(cur * 2 + dir) * B_ + bg0) * U_);
        const float4* h1 = reinterpret_cast<const float4*>(
            hbuf + ((size_t)(cur * 2 + dir) * B_ + bg1) * U_);
        #pragma unroll 8
        for (int k4 = 0; k4 < U_ / 4; ++k4) {
            float4 w = WlA[E_ / 4 + k4];
            float4 a = h0[k4];
            float4 c = h1[k4];
            acc0 = fmaf(w.x, a.x, acc0); acc0 = fmaf(w.y, a.y, acc0);
            acc0 = fmaf(w.z, a.z, acc0); acc0 = fmaf(w.w, a.w, acc0);
            acc1 = fmaf(w.x, c.x, acc1); acc1 = fmaf(w.y, c.y, acc1);
            acc1 = fmaf(w.z, c.z, acc1); acc1 = fmaf(w.w, c.w, acc1);
        }

        zx[gc * 32 + (bp * 2 + 0)] = acc0;
        zx[gc * 32 + (bp * 2 + 1)] = acc1;
        __syncthreads();

        // ---- gate + state update: one (b,u) per thread (first 256 threads) ----
        if (tid < 256) {
            const int bl = tid >> 3;
            const int vv = tid & 7;
            const int b  = b0base + bl;
            const int u  = u0 + vv;

            float zi = zx[(0 * 8 + vv) * 32 + bl];
            float zf = zx[(1 * 8 + vv) * 32 + bl];
            float zg = zx[(2 * 8 + vv) * 32 + bl];
            float zo = zx[(3 * 8 + vv) * 32 + bl];

            float c_old = cst[tid];
            float fi = tanhf(zi);
            float ff = tanhf(zf);
            float fg = tanhf(zg);
            float fo = tanhf(zo);
            float cn = fmaf(ff, c_old, fi * fg);
            float hn = fo * tanhf(cn);

            bool m = (x[b * T_ + te] != 0);
            float h_old = hbuf[((size_t)(cur * 2 + dir) * B_ + b) * U_ + u];
            float hsel = m ? hn : h_old;
            float csel = m ? cn : c_old;

            cst[tid] = csel;
            hbuf[((size_t)(nxt * 2 + dir) * B_ + b) * U_ + u] = hsel;
            out[((size_t)b * T_ + te) * 1024 + dir * 512 + u] = hsel;
            if (dir == 1 && s == T_ - 1) {
                out[(size_t)B_ * T_ * 1024 + (size_t)b * U_ + u] = hsel;
            }
        }
        grid.sync();
    }
}

extern "C" void kernel_launch(void* const* d_in, const int* in_sizes, int n_in,
                              void* d_out, int out_size, void* d_ws, size_t ws_size,
                              hipStream_t stream) {
    const int*   x   = (const int*)d_in[0];
    const float* emb = (const float*)d_in[1];
    const float* Wf  = (const float*)d_in[2];
    const float* Rf  = (const float*)d_in[3];
    const float* bfp = (const float*)d_in[4];
    const float* Wb  = (const float*)d_in[5];
    const float* Rb  = (const float*)d_in[6];
    const float* bbp = (const float*)d_in[7];
    float* out  = (float*)d_out;
    float* hbuf = (float*)d_ws;   // 2 bufs x 2 dirs x 64 x 512 floats = 512 KB

    void* args[] = {
        (void*)&x, (void*)&emb,
        (void*)&Wf, (void*)&Rf, (void*)&bfp,
        (void*)&Wb, (void*)&Rb, (void*)&bbp,
        (void*)&out, (void*)&hbuf
    };
    hipLaunchCooperativeKernel((const void*)bilstm_kernel,
                               dim3(256), dim3(512), args, 0, stream);
}

// Round 4
// 9550.713 us; speedup vs baseline: 1.4307x; 1.4307x over previous
//
#include <hip/hip_runtime.h>

#define V_ 32000
#define E_ 256
#define U_ 512
#define B_ 64
#define T_ 256
#define G_ 2048      // 4*U
#define KTOT 768     // E + U
#define WSTRIDE 772  // 768 + 4 pad

// hbuf layout (d_ws): float [2][2][B_][U_]  (cur, dir, b, u) = 512 KB
// barrier area at d_ws + 512 KB: per group g (4 groups): cnt at word g*64, flag at word g*64+32

__global__ __launch_bounds__(512, 1)
void bilstm_kernel(const int* __restrict__ x,
                   const float* __restrict__ emb,
                   const float* __restrict__ Wf, const float* __restrict__ Rf,
                   const float* __restrict__ bf,
                   const float* __restrict__ Wb, const float* __restrict__ Rb,
                   const float* __restrict__ bb,
                   float* __restrict__ out, float* __restrict__ hbuf,
                   unsigned* __restrict__ bar)
{
    __shared__ float Wl[32 * WSTRIDE];   // transposed weights [gc][k]
    __shared__ float zx[32 * 32];        // z exchange [gc][b_loc]
    __shared__ float cst[256];           // c state   [b_loc*8 + uu]

    const int blk = blockIdx.x;
    const int dir = blk >> 7;            // 0 fwd, 1 bwd
    const int rem = blk & 127;
    const int u0 = (rem >> 1) * 8;       // u-slice base
    const int b0base = (rem & 1) * 32;   // batch half
    const int grp = dir * 2 + (rem & 1); // barrier group: (dir, b-half), 64 blocks each

    unsigned* cntp  = bar + grp * 64;
    unsigned* flagp = bar + grp * 64 + 32;

    const int tid = threadIdx.x;
    const int gc  = tid & 31;            // gate-col within block (0..31)
    const int bp  = tid >> 5;            // batch pair (0..15)
    const int gate = gc >> 3;
    const int uu   = gc & 7;
    const int g    = gate * 512 + u0 + uu;   // global gate column

    const float* Wd = dir ? Wb : Wf;
    const float* Rd = dir ? Rb : Rf;
    const float* bd = dir ? bb : bf;

    // ---- one-time: stage this block's 32 weight columns into LDS, transposed ----
    for (int k = bp; k < KTOT; k += 16) {
        float v = (k < E_) ? Wd[(size_t)k * G_ + g]
                           : Rd[(size_t)(k - E_) * G_ + g];
        Wl[gc * WSTRIDE + k] = v;
    }
    if (tid < 256) cst[tid] = 0.0f;

    const float bias_g = bd[g];
    const int bg0 = b0base + bp * 2;
    const int bg1 = bg0 + 1;
    const float4* WlA = reinterpret_cast<const float4*>(&Wl[gc * WSTRIDE]);

    __syncthreads();   // Wl ready (block-local only; hbuf slot 0 zeroed by memsetAsync)

    // ---- e-part for step 0 (no h dependency) ----
    float acc0 = bias_g, acc1 = bias_g;
    {
        const int te0 = dir ? (T_ - 1) : 0;
        const float4* e0 = reinterpret_cast<const float4*>(
            emb + (size_t)x[bg0 * T_ + te0] * E_);
        const float4* e1 = reinterpret_cast<const float4*>(
            emb + (size_t)x[bg1 * T_ + te0] * E_);
        #pragma unroll 8
        for (int k4 = 0; k4 < E_ / 4; ++k4) {
            float4 w = WlA[k4];
            float4 a = e0[k4];
            float4 c = e1[k4];
            acc0 = fmaf(w.x, a.x, acc0); acc0 = fmaf(w.y, a.y, acc0);
            acc0 = fmaf(w.z, a.z, acc0); acc0 = fmaf(w.w, a.w, acc0);
            acc1 = fmaf(w.x, c.x, acc1); acc1 = fmaf(w.y, c.y, acc1);
            acc1 = fmaf(w.z, c.z, acc1); acc1 = fmaf(w.w, c.w, acc1);
        }
    }

    for (int s = 0; s < T_; ++s) {
        const int te  = dir ? (T_ - 1 - s) : s;
        const int cur = s & 1;
        const int nxt = cur ^ 1;

        // ---- wait: h_s must be visible (produced by our 64-block group at step s-1) ----
        if (s > 0) {
            if (tid == 0) {
                while (__hip_atomic_load(flagp, __ATOMIC_ACQUIRE,
                                         __HIP_MEMORY_SCOPE_AGENT) < (unsigned)s)
                    __builtin_amdgcn_s_sleep(2);
                __threadfence();   // acquire: invalidate stale L1/L2 h lines
            }
            __syncthreads();
        }

        // ---- recurrent part: h_s @ R  (K = 256..767) ----
        const float4* h0 = reinterpret_cast<const float4*>(
            hbuf + ((size_t)(cur * 2 + dir) * B_ + bg0) * U_);
        const float4* h1 = reinterpret_cast<const float4*>(
            hbuf + ((size_t)(cur * 2 + dir) * B_ + bg1) * U_);
        #pragma unroll 8
        for (int k4 = 0; k4 < U_ / 4; ++k4) {
            float4 w = WlA[E_ / 4 + k4];
            float4 a = h0[k4];
            float4 c = h1[k4];
            acc0 = fmaf(w.x, a.x, acc0); acc0 = fmaf(w.y, a.y, acc0);
            acc0 = fmaf(w.z, a.z, acc0); acc0 = fmaf(w.w, a.w, acc0);
            acc1 = fmaf(w.x, c.x, acc1); acc1 = fmaf(w.y, c.y, acc1);
            acc1 = fmaf(w.z, c.z, acc1); acc1 = fmaf(w.w, c.w, acc1);
        }

        zx[gc * 32 + (bp * 2 + 0)] = acc0;
        zx[gc * 32 + (bp * 2 + 1)] = acc1;
        __syncthreads();

        // ---- gate + state update: one (b,u) per thread (first 256 threads) ----
        if (tid < 256) {
            const int bl = tid >> 3;
            const int vv = tid & 7;
            const int b  = b0base + bl;
            const int u  = u0 + vv;

            float zi = zx[(0 * 8 + vv) * 32 + bl];
            float zf = zx[(1 * 8 + vv) * 32 + bl];
            float zg = zx[(2 * 8 + vv) * 32 + bl];
            float zo = zx[(3 * 8 + vv) * 32 + bl];

            float c_old = cst[tid];
            float fi = tanhf(zi);
            float ff = tanhf(zf);
            float fg = tanhf(zg);
            float fo = tanhf(zo);
            float cn = fmaf(ff, c_old, fi * fg);
            float hn = fo * tanhf(cn);

            bool m = (x[b * T_ + te] != 0);
            float h_old = hbuf[((size_t)(cur * 2 + dir) * B_ + b) * U_ + u];
            float hsel = m ? hn : h_old;
            float csel = m ? cn : c_old;

            cst[tid] = csel;
            hbuf[((size_t)(nxt * 2 + dir) * B_ + b) * U_ + u] = hsel;
            out[((size_t)b * T_ + te) * 1024 + dir * 512 + u] = hsel;
            if (dir == 1 && s == T_ - 1) {
                out[(size_t)B_ * T_ * 1024 + (size_t)b * U_ + u] = hsel;
            }
        }
        __syncthreads();   // h stores drained (vmcnt(0) before s_barrier)

        // ---- arrive: release h_{s+1} to the group ----
        if (tid == 0) {
            __threadfence();   // write back L2 so other XCDs see our h
            unsigned old = __hip_atomic_fetch_add(cntp, 1u, __ATOMIC_ACQ_REL,
                                                  __HIP_MEMORY_SCOPE_AGENT);
            if (old == (unsigned)(64 * (s + 1) - 1))
                __hip_atomic_store(flagp, (unsigned)(s + 1), __ATOMIC_RELEASE,
                                   __HIP_MEMORY_SCOPE_AGENT);
        }

        // ---- e-part for step s+1, hidden under barrier latency ----
        if (s + 1 < T_) {
            const int te2 = dir ? (T_ - 2 - s) : (s + 1);
            acc0 = bias_g; acc1 = bias_g;
            const float4* e0 = reinterpret_cast<const float4*>(
                emb + (size_t)x[bg0 * T_ + te2] * E_);
            const float4* e1 = reinterpret_cast<const float4*>(
                emb + (size_t)x[bg1 * T_ + te2] * E_);
            #pragma unroll 8
            for (int k4 = 0; k4 < E_ / 4; ++k4) {
                float4 w = WlA[k4];
                float4 a = e0[k4];
                float4 c = e1[k4];
                acc0 = fmaf(w.x, a.x, acc0); acc0 = fmaf(w.y, a.y, acc0);
                acc0 = fmaf(w.z, a.z, acc0); acc0 = fmaf(w.w, a.w, acc0);
                acc1 = fmaf(w.x, c.x, acc1); acc1 = fmaf(w.y, c.y, acc1);
                acc1 = fmaf(w.z, c.z, acc1); acc1 = fmaf(w.w, c.w, acc1);
            }
        }
    }
}

extern "C" void kernel_launch(void* const* d_in, const int* in_sizes, int n_in,
                              void* d_out, int out_size, void* d_ws, size_t ws_size,
                              hipStream_t stream) {
    const int*   x   = (const int*)d_in[0];
    const float* emb = (const float*)d_in[1];
    const float* Wf  = (const float*)d_in[2];
    const float* Rf  = (const float*)d_in[3];
    const float* bfp = (const float*)d_in[4];
    const float* Wb  = (const float*)d_in[5];
    const float* Rb  = (const float*)d_in[6];
    const float* bbp = (const float*)d_in[7];
    float* out  = (float*)d_out;
    float* hbuf = (float*)d_ws;                              // 512 KB: [2][2][64][512]
    unsigned* bar = (unsigned*)((char*)d_ws + 512 * 1024);   // 1 KB barrier state

    // zero h slot 0 (both dirs) and barrier counters/flags — deterministic per replay
    hipMemsetAsync(hbuf, 0, (size_t)2 * B_ * U_ * sizeof(float), stream);
    hipMemsetAsync(bar, 0, 4 * 64 * sizeof(unsigned), stream);

    void* args[] = {
        (void*)&x, (void*)&emb,
        (void*)&Wf, (void*)&Rf, (void*)&bfp,
        (void*)&Wb, (void*)&Rb, (void*)&bbp,
        (void*)&out, (void*)&hbuf, (void*)&bar
    };
    hipLaunchCooperativeKernel((const void*)bilstm_kernel,
                               dim3(256), dim3(512), args, 0, stream);
}

// Round 5
// 8050.832 us; speedup vs baseline: 1.6972x; 1.1863x over previous
//
#include <hip/hip_runtime.h>

#define V_ 32000
#define E_ 256
#define U_ 512
#define B_ 64
#define T_ 256
#define G_ 2048      // 4*U
#define KTOT 768     // E + U
#define WSTRIDE 772  // 768 + 4 pad

// d_ws layout:
//   hbuf: float [2][2][B_][U_]  (cur, dir, b, u)            = 512 KB
//   bar : at +512 KB, u32 slot per (group, member):
//         slot(g, j) = bar[(g*64 + j) * 16]   (64 B stride, line-exclusive)
//         4 groups x 64 members x 64 B = 16 KB
// Single-writer slots: block j of group g stores s+1 after producing h_{s+1}.
// No atomic RMW anywhere in the hot loop.

__global__ __launch_bounds__(512, 1)
void bilstm_kernel(const int* __restrict__ x,
                   const float* __restrict__ emb,
                   const float* __restrict__ Wf, const float* __restrict__ Rf,
                   const float* __restrict__ bf,
                   const float* __restrict__ Wb, const float* __restrict__ Rb,
                   const float* __restrict__ bb,
                   float* __restrict__ out, float* __restrict__ hbuf,
                   unsigned* __restrict__ bar)
{
    __shared__ float Wl[32 * WSTRIDE];   // transposed weights [gc][k]
    __shared__ float zx[32 * 32];        // z exchange [gc][b_loc]
    __shared__ float cst[256];           // c state   [b_loc*8 + uu]

    const int blk = blockIdx.x;
    const int dir = blk >> 7;            // 0 fwd, 1 bwd
    const int rem = blk & 127;
    const int u0 = (rem >> 1) * 8;       // u-slice base
    const int b0base = (rem & 1) * 32;   // batch half
    const int grp = dir * 2 + (rem & 1); // barrier group: (dir, b-half), 64 blocks each
    const int mem = rem >> 1;            // member index within group (0..63)

    unsigned* myslot = bar + (grp * 64 + mem) * 16;

    const int tid = threadIdx.x;
    const int gc  = tid & 31;            // gate-col within block (0..31)
    const int bp  = tid >> 5;            // batch pair (0..15)
    const int gate = gc >> 3;
    const int uu   = gc & 7;
    const int g    = gate * 512 + u0 + uu;   // global gate column

    const float* Wd = dir ? Wb : Wf;
    const float* Rd = dir ? Rb : Rf;
    const float* bd = dir ? bb : bf;

    // ---- one-time: stage this block's 32 weight columns into LDS, transposed ----
    for (int k = bp; k < KTOT; k += 16) {
        float v = (k < E_) ? Wd[(size_t)k * G_ + g]
                           : Rd[(size_t)(k - E_) * G_ + g];
        Wl[gc * WSTRIDE + k] = v;
    }
    if (tid < 256) cst[tid] = 0.0f;

    const float bias_g = bd[g];
    const int bg0 = b0base + bp * 2;
    const int bg1 = bg0 + 1;
    const float4* WlA = reinterpret_cast<const float4*>(&Wl[gc * WSTRIDE]);

    __syncthreads();   // Wl ready (hbuf slot 0 + bar zeroed by memsetAsync)

    // ---- e-part for step 0 (no h dependency) ----
    float acc0 = bias_g, acc1 = bias_g;
    {
        const int te0 = dir ? (T_ - 1) : 0;
        const float4* e0 = reinterpret_cast<const float4*>(
            emb + (size_t)x[bg0 * T_ + te0] * E_);
        const float4* e1 = reinterpret_cast<const float4*>(
            emb + (size_t)x[bg1 * T_ + te0] * E_);
        #pragma unroll 8
        for (int k4 = 0; k4 < E_ / 4; ++k4) {
            float4 w = WlA[k4];
            float4 a = e0[k4];
            float4 c = e1[k4];
            acc0 = fmaf(w.x, a.x, acc0); acc0 = fmaf(w.y, a.y, acc0);
            acc0 = fmaf(w.z, a.z, acc0); acc0 = fmaf(w.w, a.w, acc0);
            acc1 = fmaf(w.x, c.x, acc1); acc1 = fmaf(w.y, c.y, acc1);
            acc1 = fmaf(w.z, c.z, acc1); acc1 = fmaf(w.w, c.w, acc1);
        }
    }

    for (int s = 0; s < T_; ++s) {
        const int te  = dir ? (T_ - 1 - s) : s;
        const int cur = s & 1;
        const int nxt = cur ^ 1;

        // ---- wait: all 64 group members must have published h_s ----
        if (s > 0) {
            if (tid < 64) {
                unsigned* slot = bar + (grp * 64 + tid) * 16;
                while (__hip_atomic_load(slot, __ATOMIC_RELAXED,
                                         __HIP_MEMORY_SCOPE_AGENT) < (unsigned)s)
                    __builtin_amdgcn_s_sleep(1);
                // divergent-loop reconvergence == AND over all 64 slots
            }
            if (tid == 0) __threadfence();   // acquire: inv stale L1/L2 h lines
            __syncthreads();
        }

        // ---- recurrent part: h_s @ R  (K = 256..767) ----
        const float4* h0 = reinterpret_cast<const float4*>(
            hbuf + ((size_t)(cur * 2 + dir) * B_ + bg0) * U_);
        const float4* h1 = reinterpret_cast<const float4*>(
            hbuf + ((size_t)(cur * 2 + dir) * B_ + bg1) * U_);
        #pragma unroll 8
        for (int k4 = 0; k4 < U_ / 4; ++k4) {
            float4 w = WlA[E_ / 4 + k4];
            float4 a = h0[k4];
            float4 c = h1[k4];
            acc0 = fmaf(w.x, a.x, acc0); acc0 = fmaf(w.y, a.y, acc0);
            acc0 = fmaf(w.z, a.z, acc0); acc0 = fmaf(w.w, a.w, acc0);
            acc1 = fmaf(w.x, c.x, acc1); acc1 = fmaf(w.y, c.y, acc1);
            acc1 = fmaf(w.z, c.z, acc1); acc1 = fmaf(w.w, c.w, acc1);
        }

        zx[gc * 32 + (bp * 2 + 0)] = acc0;
        zx[gc * 32 + (bp * 2 + 1)] = acc1;
        __syncthreads();

        // ---- gate + state update: one (b,u) per thread (first 256 threads) ----
        if (tid < 256) {
            const int bl = tid >> 3;
            const int vv = tid & 7;
            const int b  = b0base + bl;
            const int u  = u0 + vv;

            float zi = zx[(0 * 8 + vv) * 32 + bl];
            float zf = zx[(1 * 8 + vv) * 32 + bl];
            float zg = zx[(2 * 8 + vv) * 32 + bl];
            float zo = zx[(3 * 8 + vv) * 32 + bl];

            float c_old = cst[tid];
            float fi = tanhf(zi);
            float ff = tanhf(zf);
            float fg = tanhf(zg);
            float fo = tanhf(zo);
            float cn = fmaf(ff, c_old, fi * fg);
            float hn = fo * tanhf(cn);

            bool m = (x[b * T_ + te] != 0);
            float h_old = hbuf[((size_t)(cur * 2 + dir) * B_ + b) * U_ + u];
            float hsel = m ? hn : h_old;
            float csel = m ? cn : c_old;

            cst[tid] = csel;
            hbuf[((size_t)(nxt * 2 + dir) * B_ + b) * U_ + u] = hsel;
            out[((size_t)b * T_ + te) * 1024 + dir * 512 + u] = hsel;
            if (dir == 1 && s == T_ - 1) {
                out[(size_t)B_ * T_ * 1024 + (size_t)b * U_ + u] = hsel;
            }
        }
        __syncthreads();   // h stores drained (vmcnt(0) before s_barrier)

        // ---- arrive: publish h_{s+1}; release store to private slot, no RMW ----
        if (tid == 0) {
            __threadfence();   // release: push dirty h lines past this XCD's L2
            __hip_atomic_store(myslot, (unsigned)(s + 1), __ATOMIC_RELAXED,
                               __HIP_MEMORY_SCOPE_AGENT);
        }

        // ---- e-part for step s+1, hidden under barrier latency ----
        if (s + 1 < T_) {
            const int te2 = dir ? (T_ - 2 - s) : (s + 1);
            acc0 = bias_g; acc1 = bias_g;
            const float4* e0 = reinterpret_cast<const float4*>(
                emb + (size_t)x[bg0 * T_ + te2] * E_);
            const float4* e1 = reinterpret_cast<const float4*>(
                emb + (size_t)x[bg1 * T_ + te2] * E_);
            #pragma unroll 8
            for (int k4 = 0; k4 < E_ / 4; ++k4) {
                float4 w = WlA[k4];
                float4 a = e0[k4];
                float4 c = e1[k4];
                acc0 = fmaf(w.x, a.x, acc0); acc0 = fmaf(w.y, a.y, acc0);
                acc0 = fmaf(w.z, a.z, acc0); acc0 = fmaf(w.w, a.w, acc0);
                acc1 = fmaf(w.x, c.x, acc1); acc1 = fmaf(w.y, c.y, acc1);
                acc1 = fmaf(w.z, c.z, acc1); acc1 = fmaf(w.w, c.w, acc1);
            }
        }
    }
}

extern "C" void kernel_launch(void* const* d_in, const int* in_sizes, int n_in,
                              void* d_out, int out_size, void* d_ws, size_t ws_size,
                              hipStream_t stream) {
    const int*   x   = (const int*)d_in[0];
    const float* emb = (const float*)d_in[1];
    const float* Wf  = (const float*)d_in[2];
    const float* Rf  = (const float*)d_in[3];
    const float* bfp = (const float*)d_in[4];
    const float* Wb  = (const float*)d_in[5];
    const float* Rb  = (const float*)d_in[6];
    const float* bbp = (const float*)d_in[7];
    float* out  = (float*)d_out;
    float* hbuf = (float*)d_ws;                              // 512 KB: [2][2][64][512]
    unsigned* bar = (unsigned*)((char*)d_ws + 512 * 1024);   // 16 KB slot array

    // zero h slot 0 (both dirs) + barrier slots — re-run on every graph replay
    hipMemsetAsync(hbuf, 0, (size_t)2 * B_ * U_ * sizeof(float), stream);
    hipMemsetAsync(bar, 0, 4 * 64 * 16 * sizeof(unsigned), stream);

    void* args[] = {
        (void*)&x, (void*)&emb,
        (void*)&Wf, (void*)&Rf, (void*)&bfp,
        (void*)&Wb, (void*)&Rb, (void*)&bbp,
        (void*)&out, (void*)&hbuf, (void*)&bar
    };
    hipLaunchCooperativeKernel((const void*)bilstm_kernel,
                               dim3(256), dim3(512), args, 0, stream);
}

// Round 6
// 7902.450 us; speedup vs baseline: 1.7291x; 1.0188x over previous
//
#include <hip/hip_runtime.h>

#define V_ 32000
#define E_ 256
#define U_ 512
#define B_ 64
#define T_ 256
#define G_ 2048      // 4*U

#define RSTR 516     // R rows / scan-h rows: 512 data + 4 pad floats (conflict-free)
#define ASTR 260     // precompute A rows: 256 data + 4 pad
#define WESTR 132    // We rows: 128 data + 4 pad

// d_ws layout:
//   [0, 512KB)   : hbuf float [2][2][B_][U_] (cur, dir, b, u)
//   [512KB, +16K): barrier slots, u32 at (grp*64+mem)*16 (64B stride)
//   [1MB, 1MB+CH*1MB): xz chunk buffer [256 blk][CH][32 gc][32 b] floats
// Requires ws_size >= (CH+1) MB; CH adaptively shrunk 32->2.

#define GLDS16(gsrc, ldst) __builtin_amdgcn_global_load_lds( \
    (const __attribute__((address_space(1))) void*)(gsrc),    \
    (__attribute__((address_space(3))) void*)(ldst), 16, 0, 0)

__global__ __launch_bounds__(256, 1)
void bilstm_kernel(const int* __restrict__ x,
                   const float* __restrict__ emb,
                   const float* __restrict__ Wf, const float* __restrict__ Rf,
                   const float* __restrict__ bf,
                   const float* __restrict__ Wb, const float* __restrict__ Rb,
                   const float* __restrict__ bb,
                   float* __restrict__ out, float* __restrict__ hbuf,
                   unsigned* __restrict__ bar, float* __restrict__ xz,
                   int CH)
{
    __shared__ float Rl[32 * RSTR];     // 66,048 B : R transposed [gc][k]
    __shared__ float HA[64 * ASTR];     // 66,560 B : union scan-h [32][516] / A [64][260]
    __shared__ float Wel[32 * WESTR];   // 16,896 B : W k-half transposed [gc][kk]

    const int blk = blockIdx.x;
    const int dir = blk >> 7;            // 0 fwd, 1 bwd
    const int rem = blk & 127;
    const int u0 = (rem >> 1) * 8;       // u-slice base
    const int b0base = (rem & 1) * 32;   // batch half
    const int grp = dir * 2 + (rem & 1); // barrier group (dir, b-half): 64 blocks
    const int mem = rem >> 1;
    unsigned* myslot = bar + (grp * 64 + mem) * 16;

    const int tid  = threadIdx.x;        // 256 threads
    const int wv   = tid >> 6;           // wave 0..3
    const int lane = tid & 63;
    const int bl   = tid >> 3;           // local batch 0..31 (cell row)
    const int uu   = tid & 7;            // u within slice  (cell col)

    const float* Wd = dir ? Wb : Wf;
    const float* Rd = dir ? Rb : Rf;
    const float* bd = dir ? bb : bf;

    // ---- one-time: stage R transposed into LDS ----
    {
        const int sgc  = tid & 31;
        const int gcol = ((sgc >> 3) * 512) + u0 + (sgc & 7);
        for (int k = tid >> 5; k < 512; k += 8)
            Rl[sgc * RSTR + k] = Rd[(size_t)k * G_ + gcol];
    }
    float bias4[4];
    #pragma unroll
    for (int g = 0; g < 4; ++g) bias4[g] = bd[g * 512 + u0 + uu];

    float c_reg = 0.0f;
    const float4* Rl4  = reinterpret_cast<const float4*>(Rl);
    const float4* HA4  = reinterpret_cast<const float4*>(HA);
    const float4* Wel4 = reinterpret_cast<const float4*>(Wel);

    const int nch = T_ / CH;
    for (int ch = 0; ch < nch; ++ch) {
        // ============ precompute xz = e@W + bias for this chunk (block-local) ============
        const int nat = CH >> 1;                 // A-tiles of 2 t x 32 b
        for (int at = 0; at < nat; ++at) {
            __syncthreads();                     // HA free (prev reads done)
            // stage A: 64 rows x 1KB via global_load_lds (one wave-op per row)
            for (int i = 0; i < 16; ++i) {
                int rr   = wv * 16 + i;          // 0..63
                int tloc = at * 2 + (rr >> 5);
                int bla  = rr & 31;
                int sg   = ch * CH + tloc;
                int tea  = dir ? (T_ - 1 - sg) : sg;
                int tok  = x[(b0base + bla) * T_ + tea];
                GLDS16(emb + (size_t)tok * E_ + lane * 4, HA + rr * ASTR);
            }
            float pacc[8];
            #pragma unroll
            for (int i = 0; i < 8; ++i) pacc[i] = 0.0f;
            const int r0 = (tid >> 3) * 2;
            const int r1 = r0 + 1;
            for (int kh = 0; kh < 2; ++kh) {
                if (kh) __syncthreads();         // gemm half0 done before Wel overwrite
                {
                    const int sgc  = tid & 31;
                    const int gcol = ((sgc >> 3) * 512) + u0 + (sgc & 7);
                    for (int kk = tid >> 5; kk < 128; kk += 8)
                        Wel[sgc * WESTR + kk] = Wd[(size_t)(kh * 128 + kk) * G_ + gcol];
                }
                __syncthreads();                 // A (glds drained) + Wel visible
                #pragma unroll 2
                for (int k4 = 0; k4 < 32; ++k4) {
                    float4 a0 = HA4[r0 * 65 + kh * 32 + k4];
                    float4 a1 = HA4[r1 * 65 + kh * 32 + k4];
                    #pragma unroll
                    for (int g = 0; g < 4; ++g) {
                        float4 w = Wel4[(g * 8 + uu) * 33 + k4];
                        pacc[g*2]   = fmaf(w.x, a0.x, pacc[g*2]);
                        pacc[g*2]   = fmaf(w.y, a0.y, pacc[g*2]);
                        pacc[g*2]   = fmaf(w.z, a0.z, pacc[g*2]);
                        pacc[g*2]   = fmaf(w.w, a0.w, pacc[g*2]);
                        pacc[g*2+1] = fmaf(w.x, a1.x, pacc[g*2+1]);
                        pacc[g*2+1] = fmaf(w.y, a1.y, pacc[g*2+1]);
                        pacc[g*2+1] = fmaf(w.z, a1.z, pacc[g*2+1]);
                        pacc[g*2+1] = fmaf(w.w, a1.w, pacc[g*2+1]);
                    }
                }
            }
            #pragma unroll
            for (int g = 0; g < 4; ++g) {
                const int gcg = g * 8 + uu;
                int tl0 = at * 2 + (r0 >> 5), bl0 = r0 & 31;
                int tl1 = at * 2 + (r1 >> 5), bl1 = r1 & 31;
                xz[((size_t)blk * CH + tl0) * 1024 + gcg * 32 + bl0] = pacc[g*2]   + bias4[g];
                xz[((size_t)blk * CH + tl1) * 1024 + gcg * 32 + bl1] = pacc[g*2+1] + bias4[g];
            }
        }
        __syncthreads();   // precompute done; HA reusable for scan

        // ============ scan CH steps ============
        for (int sc = 0; sc < CH; ++sc) {
            const int s   = ch * CH + sc;
            const int te  = dir ? (T_ - 1 - s) : s;
            const int cur = s & 1, nxt = cur ^ 1;

            // wait: all 64 group members published h_s
            if (s > 0) {
                if (tid < 64) {
                    unsigned* slot = bar + (grp * 64 + tid) * 16;
                    while (__hip_atomic_load(slot, __ATOMIC_RELAXED,
                                             __HIP_MEMORY_SCOPE_AGENT) < (unsigned)s)
                        __builtin_amdgcn_s_sleep(1);
                }
                if (tid == 0) __threadfence();   // acquire
                __syncthreads();
            }
            // stage h_s -> LDS (32 rows x 2KB, 2 glds per row)
            {
                const float* hsrc = hbuf + ((size_t)(cur * 2 + dir) * B_ + b0base) * U_;
                for (int i = 0; i < 16; ++i) {
                    int rr = wv * 16 + i;        // 0..63
                    int row = rr >> 1, half = rr & 1;
                    GLDS16(hsrc + row * U_ + half * 256 + lane * 4,
                           HA + row * RSTR + half * 256);
                }
            }
            float acc[4];
            {
                const float* xzp = xz + ((size_t)blk * CH + sc) * 1024;
                #pragma unroll
                for (int g = 0; g < 4; ++g) acc[g] = xzp[(g * 8 + uu) * 32 + bl];
            }
            const int mtok = x[(b0base + bl) * T_ + te];
            __syncthreads();   // h staged (vmcnt drained before barrier)

            // z[g] = xz + h @ R  for this thread's 4 gate columns
            #pragma unroll 2
            for (int k4 = 0; k4 < 128; ++k4) {
                float4 hv = HA4[bl * 129 + k4];
                #pragma unroll
                for (int g = 0; g < 4; ++g) {
                    float4 w = Rl4[(g * 8 + uu) * 129 + k4];
                    acc[g] = fmaf(w.x, hv.x, acc[g]);
                    acc[g] = fmaf(w.y, hv.y, acc[g]);
                    acc[g] = fmaf(w.z, hv.z, acc[g]);
                    acc[g] = fmaf(w.w, hv.w, acc[g]);
                }
            }
            float fi = tanhf(acc[0]);
            float ff = tanhf(acc[1]);
            float fg = tanhf(acc[2]);
            float fo = tanhf(acc[3]);
            float cn = fmaf(ff, c_reg, fi * fg);
            float hn = fo * tanhf(cn);
            float h_old = HA[bl * RSTR + u0 + uu];
            bool  m  = (mtok != 0);
            float hsel = m ? hn : h_old;
            c_reg = m ? cn : c_reg;

            const int b = b0base + bl;
            hbuf[((size_t)(nxt * 2 + dir) * B_ + b) * U_ + u0 + uu] = hsel;
            out[((size_t)b * T_ + te) * 1024 + dir * 512 + u0 + uu] = hsel;
            if (dir == 1 && s == T_ - 1)
                out[(size_t)B_ * T_ * 1024 + (size_t)b * U_ + u0 + uu] = hsel;

            __syncthreads();   // all waves' h stores drained (vmcnt0 before barrier)
            if (tid == 0) {
                __threadfence();                 // release
                __hip_atomic_store(myslot, (unsigned)(s + 1), __ATOMIC_RELAXED,
                                   __HIP_MEMORY_SCOPE_AGENT);
            }
        }
    }
}

extern "C" void kernel_launch(void* const* d_in, const int* in_sizes, int n_in,
                              void* d_out, int out_size, void* d_ws, size_t ws_size,
                              hipStream_t stream) {
    const int*   x   = (const int*)d_in[0];
    const float* emb = (const float*)d_in[1];
    const float* Wf  = (const float*)d_in[2];
    const float* Rf  = (const float*)d_in[3];
    const float* bfp = (const float*)d_in[4];
    const float* Wb  = (const float*)d_in[5];
    const float* Rb  = (const float*)d_in[6];
    const float* bbp = (const float*)d_in[7];
    float* out  = (float*)d_out;
    float* hbuf = (float*)d_ws;                                   // 512 KB
    unsigned* bar = (unsigned*)((char*)d_ws + 512 * 1024);        // 16 KB
    float* xzbuf  = (float*)((char*)d_ws + (1 << 20));            // CH MB

    int CH = 32;
    while (CH > 2 && (size_t)(CH + 1) * (1 << 20) > ws_size) CH >>= 1;

    hipMemsetAsync(hbuf, 0, (size_t)2 * B_ * U_ * sizeof(float), stream);
    hipMemsetAsync(bar, 0, 4 * 64 * 16 * sizeof(unsigned), stream);

    void* args[] = {
        (void*)&x, (void*)&emb,
        (void*)&Wf, (void*)&Rf, (void*)&bfp,
        (void*)&Wb, (void*)&Rb, (void*)&bbp,
        (void*)&out, (void*)&hbuf, (void*)&bar, (void*)&xzbuf, (void*)&CH
    };
    hipLaunchCooperativeKernel((const void*)bilstm_kernel,
                               dim3(256), dim3(256), args, 0, stream);
}

// Round 8
// 5234.677 us; speedup vs baseline: 2.6102x; 1.5096x over previous
//
#include <hip/hip_runtime.h>

#define V_ 32000
#define E_ 256
#define U_ 512
#define B_ 64
#define T_ 256
#define G_ 2048      // 4*U

#define RSTR 516     // R rows / scan-h rows: 512 data + 4 pad floats
#define ASTR 260     // precompute A rows: 256 data + 4 pad
#define WESTR 132    // We rows: 128 data + 4 pad

// d_ws layout:
//   [0, 512KB)   : hbuf float [2][2][B_][U_] (cur, dir, b, u)
//   [512KB, +16K): barrier slots, u32 at (grp*64+mem)*16 (64B stride)
//   [1MB, ...)   : xz chunk buffer [256 blk][CH][32 gc][32 b] floats
// Coherence: h stores are relaxed agent-scope atomics (write-through to MALL);
// consumers invalidate L2 via acquire fence before staging h. Slot protocol
// unchanged from round 4 (single-writer, 64B-strided slots).

#define GLDS16(gsrc, ldst) __builtin_amdgcn_global_load_lds( \
    (const __attribute__((address_space(1))) void*)(gsrc),    \
    (__attribute__((address_space(3))) void*)(ldst), 16, 0, 0)

__global__ __launch_bounds__(256, 1)
void bilstm_kernel(const int* __restrict__ x,
                   const float* __restrict__ emb,
                   const float* __restrict__ Wf, const float* __restrict__ Rf,
                   const float* __restrict__ bf,
                   const float* __restrict__ Wb, const float* __restrict__ Rb,
                   const float* __restrict__ bb,
                   float* __restrict__ out, float* __restrict__ hbuf,
                   unsigned* __restrict__ bar, float* __restrict__ xz,
                   int CH)
{
    __shared__ __align__(16) float Rl[32 * RSTR];     // 66,048 B
    __shared__ __align__(16) float HA[64 * ASTR];     // 66,560 B (A / scan-h / pre-reduce)
    __shared__ __align__(16) float Wel[32 * WESTR];   // 16,896 B (W-half / scan-reduce)

    const int blk = blockIdx.x;
    const int dir = blk >> 7;
    const int rem = blk & 127;
    const int u0 = (rem >> 1) * 8;
    const int b0base = (rem & 1) * 32;
    const int grp = dir * 2 + (rem & 1);
    const int mem = rem >> 1;
    unsigned* myslot = bar + (grp * 64 + mem) * 16;

    const int tid   = threadIdx.x;       // 256
    const int wv    = tid >> 6;          // wave 0..3 (owns k-slice)
    const int lane  = tid & 63;
    const int uu    = lane & 7;          // gate-col sub-index
    const int blgrp = lane >> 3;         // 0..7
    const int bl    = tid >> 3;          // finalize mapping: batch 0..31
    const int fuu   = tid & 7;           // finalize mapping: u sub-index

    const float* Wd = dir ? Wb : Wf;
    const float* Rd = dir ? Rb : Rf;
    const float* bd = dir ? bb : bf;

    // ---- one-time: stage R transposed into LDS ----
    {
        const int sgc  = tid & 31;
        const int gcol = ((sgc >> 3) * 512) + u0 + (sgc & 7);
        for (int k = tid >> 5; k < 512; k += 8)
            Rl[sgc * RSTR + k] = Rd[(size_t)k * G_ + gcol];
    }
    float bias4[4];
    #pragma unroll
    for (int g = 0; g < 4; ++g) bias4[g] = bd[g * 512 + u0 + fuu];

    float c_reg = 0.0f;
    const float4* Rl4  = reinterpret_cast<const float4*>(Rl);
    const float4* HA4  = reinterpret_cast<const float4*>(HA);
    const float4* Wel4 = reinterpret_cast<const float4*>(Wel);
    float4* P4s = reinterpret_cast<float4*>(Wel);   // scan reduce buffer (16 KB)
    float4* P4p = reinterpret_cast<float4*>(HA);    // precompute reduce buffer (32 KB)

    __syncthreads();

    const int nch = T_ / CH;
    for (int ch = 0; ch < nch; ++ch) {
        // ============ precompute xz = e@W for this chunk (k-split GEMM) ============
        const int nat = CH >> 1;                     // A-tiles of 2t x 32b
        for (int at = 0; at < nat; ++at) {
            __syncthreads();                         // HA & Wel free
            // stage A: 64 rows x 1KB
            for (int i = 0; i < 16; ++i) {
                int rr   = wv * 16 + i;
                int tloc = at * 2 + (rr >> 5);
                int bla  = rr & 31;
                int sg   = ch * CH + tloc;
                int tea  = dir ? (T_ - 1 - sg) : sg;
                int tok  = x[(b0base + bla) * T_ + tea];
                GLDS16(emb + (size_t)tok * E_ + lane * 4, HA + rr * ASTR);
            }
            float pacc[8][4];
            #pragma unroll
            for (int j = 0; j < 8; ++j)
                #pragma unroll
                for (int g = 0; g < 4; ++g) pacc[j][g] = 0.0f;

            for (int kh = 0; kh < 2; ++kh) {
                if (kh) __syncthreads();             // Wel half-0 reads done
                {
                    const int sgc  = tid & 31;
                    const int gcol = ((sgc >> 3) * 512) + u0 + (sgc & 7);
                    for (int kk = tid >> 5; kk < 128; kk += 8)
                        Wel[sgc * WESTR + kk] = Wd[(size_t)(kh * 128 + kk) * G_ + gcol];
                }
                __syncthreads();                     // A (vmcnt drained) + Wel ready
                #pragma unroll 2
                for (int k4 = 0; k4 < 8; ++k4) {
                    const int kw = wv * 8 + k4;      // k4-index within half
                    float4 w0 = Wel4[(0 * 8 + uu) * 33 + kw];
                    float4 w1 = Wel4[(1 * 8 + uu) * 33 + kw];
                    float4 w2 = Wel4[(2 * 8 + uu) * 33 + kw];
                    float4 w3 = Wel4[(3 * 8 + uu) * 33 + kw];
                    #pragma unroll
                    for (int j = 0; j < 8; ++j) {
                        float4 a = HA4[(blgrp + 8 * j) * 65 + kh * 32 + kw];
                        pacc[j][0] = fmaf(w0.x,a.x,pacc[j][0]); pacc[j][0] = fmaf(w0.y,a.y,pacc[j][0]);
                        pacc[j][0] = fmaf(w0.z,a.z,pacc[j][0]); pacc[j][0] = fmaf(w0.w,a.w,pacc[j][0]);
                        pacc[j][1] = fmaf(w1.x,a.x,pacc[j][1]); pacc[j][1] = fmaf(w1.y,a.y,pacc[j][1]);
                        pacc[j][1] = fmaf(w1.z,a.z,pacc[j][1]); pacc[j][1] = fmaf(w1.w,a.w,pacc[j][1]);
                        pacc[j][2] = fmaf(w2.x,a.x,pacc[j][2]); pacc[j][2] = fmaf(w2.y,a.y,pacc[j][2]);
                        pacc[j][2] = fmaf(w2.z,a.z,pacc[j][2]); pacc[j][2] = fmaf(w2.w,a.w,pacc[j][2]);
                        pacc[j][3] = fmaf(w3.x,a.x,pacc[j][3]); pacc[j][3] = fmaf(w3.y,a.y,pacc[j][3]);
                        pacc[j][3] = fmaf(w3.z,a.z,pacc[j][3]); pacc[j][3] = fmaf(w3.w,a.w,pacc[j][3]);
                    }
                }
            }
            __syncthreads();                         // A reads done -> HA reusable
            #pragma unroll
            for (int j = 0; j < 8; ++j)
                P4p[(wv * 64 + blgrp + 8 * j) * 8 + uu] =
                    float4{pacc[j][0], pacc[j][1], pacc[j][2], pacc[j][3]};
            __syncthreads();                         // partials ready
            {
                const int r   = tid >> 2;            // token row 0..63
                const int up  = tid & 3;
                const int tl  = at * 2 + (r >> 5);
                const int bla = r & 31;
                float* dst = xz + ((size_t)blk * CH + tl) * 1024;
                #pragma unroll
                for (int q = 0; q < 2; ++q) {
                    const int uq = up + q * 4;
                    float4 s0 = P4p[(0 * 64 + r) * 8 + uq];
                    float4 s1 = P4p[(1 * 64 + r) * 8 + uq];
                    float4 s2 = P4p[(2 * 64 + r) * 8 + uq];
                    float4 s3 = P4p[(3 * 64 + r) * 8 + uq];
                    dst[(0 * 8 + uq) * 32 + bla] = s0.x + s1.x + s2.x + s3.x;
                    dst[(1 * 8 + uq) * 32 + bla] = s0.y + s1.y + s2.y + s3.y;
                    dst[(2 * 8 + uq) * 32 + bla] = s0.z + s1.z + s2.z + s3.z;
                    dst[(3 * 8 + uq) * 32 + bla] = s0.w + s1.w + s2.w + s3.w;
                }
            }
        }
        __syncthreads();

        // ============ scan CH steps ============
        for (int sc = 0; sc < CH; ++sc) {
            const int s   = ch * CH + sc;
            const int te  = dir ? (T_ - 1 - s) : s;
            const int cur = s & 1, nxt = cur ^ 1;

            if (s > 0) {
                if (tid < 64) {
                    unsigned* slot = bar + (grp * 64 + tid) * 16;
                    while (__hip_atomic_load(slot, __ATOMIC_RELAXED,
                                             __HIP_MEMORY_SCOPE_AGENT) < (unsigned)s)
                        __builtin_amdgcn_s_sleep(1);
                }
                __builtin_amdgcn_fence(__ATOMIC_ACQUIRE, "agent");  // inv L2 (no wbl2)
                __syncthreads();
            }
            // stage h_s -> LDS [32][RSTR]
            {
                const float* hsrc = hbuf + ((size_t)(cur * 2 + dir) * B_ + b0base) * U_;
                for (int i = 0; i < 16; ++i) {
                    int rr = wv * 16 + i;
                    int row = rr >> 1, half = rr & 1;
                    GLDS16(hsrc + row * U_ + half * 256 + lane * 4,
                           HA + row * RSTR + half * 256);
                }
            }
            const int mtok = x[(b0base + bl) * T_ + te];
            float xzv[4];
            {
                const float* xzp = xz + ((size_t)blk * CH + sc) * 1024;
                #pragma unroll
                for (int g = 0; g < 4; ++g)
                    xzv[g] = xzp[(g * 8 + fuu) * 32 + bl] + bias4[g];
            }
            __syncthreads();                         // h staged (vmcnt drained)

            // partial z: this wave's k-slice, rows blgrp+8j, gates 0..3 (col uu)
            float pz[4][4];
            #pragma unroll
            for (int j = 0; j < 4; ++j)
                #pragma unroll
                for (int g = 0; g < 4; ++g) pz[j][g] = 0.0f;
            const int kbase = wv * 32;
            #pragma unroll 8
            for (int k4 = 0; k4 < 32; ++k4) {
                const int kk = kbase + k4;
                float4 h0 = HA4[(blgrp + 8 * 0) * 129 + kk];
                float4 h1 = HA4[(blgrp + 8 * 1) * 129 + kk];
                float4 h2 = HA4[(blgrp + 8 * 2) * 129 + kk];
                float4 h3 = HA4[(blgrp + 8 * 3) * 129 + kk];
                #pragma unroll
                for (int g = 0; g < 4; ++g) {
                    float4 w = Rl4[(g * 8 + uu) * 129 + kk];
                    pz[0][g] = fmaf(w.x,h0.x,pz[0][g]); pz[0][g] = fmaf(w.y,h0.y,pz[0][g]);
                    pz[0][g] = fmaf(w.z,h0.z,pz[0][g]); pz[0][g] = fmaf(w.w,h0.w,pz[0][g]);
                    pz[1][g] = fmaf(w.x,h1.x,pz[1][g]); pz[1][g] = fmaf(w.y,h1.y,pz[1][g]);
                    pz[1][g] = fmaf(w.z,h1.z,pz[1][g]); pz[1][g] = fmaf(w.w,h1.w,pz[1][g]);
                    pz[2][g] = fmaf(w.x,h2.x,pz[2][g]); pz[2][g] = fmaf(w.y,h2.y,pz[2][g]);
                    pz[2][g] = fmaf(w.z,h2.z,pz[2][g]); pz[2][g] = fmaf(w.w,h2.w,pz[2][g]);
                    pz[3][g] = fmaf(w.x,h3.x,pz[3][g]); pz[3][g] = fmaf(w.y,h3.y,pz[3][g]);
                    pz[3][g] = fmaf(w.w,h3.w,pz[3][g]); pz[3][g] = fmaf(w.z,h3.z,pz[3][g]);
                }
            }
            float h_old = HA[bl * RSTR + u0 + fuu];
            #pragma unroll
            for (int j = 0; j < 4; ++j)
                P4s[(wv * 32 + blgrp + 8 * j) * 8 + uu] =
                    float4{pz[j][0], pz[j][1], pz[j][2], pz[j][3]};
            __syncthreads();                         // partials ready

            float4 z0 = P4s[(0 * 32 + bl) * 8 + fuu];
            float4 z1 = P4s[(1 * 32 + bl) * 8 + fuu];
            float4 z2 = P4s[(2 * 32 + bl) * 8 + fuu];
            float4 z3 = P4s[(3 * 32 + bl) * 8 + fuu];
            float fi = tanhf(z0.x + z1.x + z2.x + z3.x + xzv[0]);
            float ff = tanhf(z0.y + z1.y + z2.y + z3.y + xzv[1]);
            float fg = tanhf(z0.z + z1.z + z2.z + z3.z + xzv[2]);
            float fo = tanhf(z0.w + z1.w + z2.w + z3.w + xzv[3]);
            float cn = fmaf(ff, c_reg, fi * fg);
            float hn = fo * tanhf(cn);
            bool  m  = (mtok != 0);
            float hsel = m ? hn : h_old;
            c_reg = m ? cn : c_reg;

            const int b = b0base + bl;
            __hip_atomic_store(&hbuf[((size_t)(nxt * 2 + dir) * B_ + b) * U_ + u0 + fuu],
                               hsel, __ATOMIC_RELAXED, __HIP_MEMORY_SCOPE_AGENT);
            out[((size_t)b * T_ + te) * 1024 + dir * 512 + u0 + fuu] = hsel;
            if (dir == 1 && s == T_ - 1)
                out[(size_t)B_ * T_ * 1024 + (size_t)b * U_ + u0 + fuu] = hsel;

            __syncthreads();       // vmcnt(0) drain: h write-through complete
            if (tid == 0)
                __hip_atomic_store(myslot, (unsigned)(s + 1), __ATOMIC_RELAXED,
                                   __HIP_MEMORY_SCOPE_AGENT);
        }
    }
}

extern "C" void kernel_launch(void* const* d_in, const int* in_sizes, int n_in,
                              void* d_out, int out_size, void* d_ws, size_t ws_size,
                              hipStream_t stream) {
    const int*   x   = (const int*)d_in[0];
    const float* emb = (const float*)d_in[1];
    const float* Wf  = (const float*)d_in[2];
    const float* Rf  = (const float*)d_in[3];
    const float* bfp = (const float*)d_in[4];
    const float* Wb  = (const float*)d_in[5];
    const float* Rb  = (const float*)d_in[6];
    const float* bbp = (const float*)d_in[7];
    float* out  = (float*)d_out;
    float* hbuf = (float*)d_ws;                                   // 512 KB
    unsigned* bar = (unsigned*)((char*)d_ws + 512 * 1024);        // 16 KB
    float* xzbuf  = (float*)((char*)d_ws + (1 << 20));            // CH MB

    int CH = 32;
    while (CH > 2 && (size_t)(CH + 1) * (1 << 20) > ws_size) CH >>= 1;

    hipMemsetAsync(hbuf, 0, (size_t)2 * B_ * U_ * sizeof(float), stream);
    hipMemsetAsync(bar, 0, 4 * 64 * 16 * sizeof(unsigned), stream);

    void* args[] = {
        (void*)&x, (void*)&emb,
        (void*)&Wf, (void*)&Rf, (void*)&bfp,
        (void*)&Wb, (void*)&Rb, (void*)&bbp,
        (void*)&out, (void*)&hbuf, (void*)&bar, (void*)&xzbuf, (void*)&CH
    };
    hipLaunchCooperativeKernel((const void*)bilstm_kernel,
                               dim3(256), dim3(256), args, 0, stream);
}

// Round 9
// 4313.593 us; speedup vs baseline: 3.1676x; 1.2135x over previous
//
#include <hip/hip_runtime.h>

#define V_ 32000
#define E_ 256
#define U_ 512
#define B_ 64
#define T_ 256
#define G_ 2048      // 4*U

#define RSTR 516     // R rows / scan-h rows: 512 data + 4 pad floats
#define ASTR 260     // precompute A rows: 256 data + 4 pad
#define WESTR 132    // We rows: 128 data + 4 pad

// d_ws layout:
//   [0, 512KB)   : hbuf float [2][2][B_][U_] (cur, dir, b, u)
//   [512KB, +16K): barrier slots, u32 at (grp*64+mem)*16 (64B stride)
//   [1MB, ...)   : xz chunk buffer [256 blk][CH][32 gc][32 b] floats
// Coherence (NO L2 invalidation anywhere):
//   h stores  : relaxed agent-scope atomic stores (write-through to MALL)
//   h loads   : relaxed agent-scope atomic loads (L2-bypassing, MALL-coherent)
//   slots     : relaxed agent-scope atomics, single-writer 64B-strided
//   ordering  : producer drains stores at __syncthreads (vmcnt0) before publish;
//               consumer polls, __syncthreads, then stages h.

#define GLDS16(gsrc, ldst) __builtin_amdgcn_global_load_lds( \
    (const __attribute__((address_space(1))) void*)(gsrc),    \
    (__attribute__((address_space(3))) void*)(ldst), 16, 0, 0)

__global__ __launch_bounds__(256, 1)
void bilstm_kernel(const int* __restrict__ x,
                   const float* __restrict__ emb,
                   const float* __restrict__ Wf, const float* __restrict__ Rf,
                   const float* __restrict__ bf,
                   const float* __restrict__ Wb, const float* __restrict__ Rb,
                   const float* __restrict__ bb,
                   float* __restrict__ out, float* __restrict__ hbuf,
                   unsigned* __restrict__ bar, float* __restrict__ xz,
                   int CH)
{
    __shared__ __align__(16) float Rl[32 * RSTR];     // 66,048 B
    __shared__ __align__(16) float HA[64 * ASTR];     // 66,560 B (A / scan-h / pre-reduce)
    __shared__ __align__(16) float Wel[32 * WESTR];   // 16,896 B (W-half / scan-reduce)

    const int blk = blockIdx.x;
    const int dir = blk >> 7;
    const int rem = blk & 127;
    const int u0 = (rem >> 1) * 8;
    const int b0base = (rem & 1) * 32;
    const int grp = dir * 2 + (rem & 1);
    const int mem = rem >> 1;
    unsigned* myslot = bar + (grp * 64 + mem) * 16;

    const int tid   = threadIdx.x;       // 256
    const int wv    = tid >> 6;          // wave 0..3 (owns k-slice)
    const int lane  = tid & 63;
    const int uu    = lane & 7;          // gate-col sub-index
    const int blgrp = lane >> 3;         // 0..7
    const int bl    = tid >> 3;          // finalize mapping: batch 0..31
    const int fuu   = tid & 7;           // finalize mapping: u sub-index

    const float* Wd = dir ? Wb : Wf;
    const float* Rd = dir ? Rb : Rf;
    const float* bd = dir ? bb : bf;

    // ---- one-time: stage R transposed into LDS ----
    {
        const int sgc  = tid & 31;
        const int gcol = ((sgc >> 3) * 512) + u0 + (sgc & 7);
        for (int k = tid >> 5; k < 512; k += 8)
            Rl[sgc * RSTR + k] = Rd[(size_t)k * G_ + gcol];
    }
    float bias4[4];
    #pragma unroll
    for (int g = 0; g < 4; ++g) bias4[g] = bd[g * 512 + u0 + fuu];

    float c_reg = 0.0f;
    const float4* Rl4  = reinterpret_cast<const float4*>(Rl);
    const float4* HA4  = reinterpret_cast<const float4*>(HA);
    const float4* Wel4 = reinterpret_cast<const float4*>(Wel);
    float4* HAw4 = reinterpret_cast<float4*>(HA);   // staging writes
    float4* P4s = reinterpret_cast<float4*>(Wel);   // scan reduce buffer (16 KB)
    float4* P4p = reinterpret_cast<float4*>(HA);    // precompute reduce buffer (32 KB)

    __syncthreads();

    const int nch = T_ / CH;
    for (int ch = 0; ch < nch; ++ch) {
        // ============ precompute xz = e@W for this chunk (k-split GEMM) ============
        const int nat = CH >> 1;                     // A-tiles of 2t x 32b
        for (int at = 0; at < nat; ++at) {
            __syncthreads();                         // HA & Wel free
            // stage A: 64 rows x 1KB (emb is read-only, L2-warm: plain GLDS)
            for (int i = 0; i < 16; ++i) {
                int rr   = wv * 16 + i;
                int tloc = at * 2 + (rr >> 5);
                int bla  = rr & 31;
                int sg   = ch * CH + tloc;
                int tea  = dir ? (T_ - 1 - sg) : sg;
                int tok  = x[(b0base + bla) * T_ + tea];
                GLDS16(emb + (size_t)tok * E_ + lane * 4, HA + rr * ASTR);
            }
            float pacc[8][4];
            #pragma unroll
            for (int j = 0; j < 8; ++j)
                #pragma unroll
                for (int g = 0; g < 4; ++g) pacc[j][g] = 0.0f;

            for (int kh = 0; kh < 2; ++kh) {
                if (kh) __syncthreads();             // Wel half-0 reads done
                {
                    const int sgc  = tid & 31;
                    const int gcol = ((sgc >> 3) * 512) + u0 + (sgc & 7);
                    for (int kk = tid >> 5; kk < 128; kk += 8)
                        Wel[sgc * WESTR + kk] = Wd[(size_t)(kh * 128 + kk) * G_ + gcol];
                }
                __syncthreads();                     // A (vmcnt drained) + Wel ready
                #pragma unroll 2
                for (int k4 = 0; k4 < 8; ++k4) {
                    const int kw = wv * 8 + k4;      // k4-index within half
                    float4 w0 = Wel4[(0 * 8 + uu) * 33 + kw];
                    float4 w1 = Wel4[(1 * 8 + uu) * 33 + kw];
                    float4 w2 = Wel4[(2 * 8 + uu) * 33 + kw];
                    float4 w3 = Wel4[(3 * 8 + uu) * 33 + kw];
                    #pragma unroll
                    for (int j = 0; j < 8; ++j) {
                        float4 a = HA4[(blgrp + 8 * j) * 65 + kh * 32 + kw];
                        pacc[j][0] = fmaf(w0.x,a.x,pacc[j][0]); pacc[j][0] = fmaf(w0.y,a.y,pacc[j][0]);
                        pacc[j][0] = fmaf(w0.z,a.z,pacc[j][0]); pacc[j][0] = fmaf(w0.w,a.w,pacc[j][0]);
                        pacc[j][1] = fmaf(w1.x,a.x,pacc[j][1]); pacc[j][1] = fmaf(w1.y,a.y,pacc[j][1]);
                        pacc[j][1] = fmaf(w1.z,a.z,pacc[j][1]); pacc[j][1] = fmaf(w1.w,a.w,pacc[j][1]);
                        pacc[j][2] = fmaf(w2.x,a.x,pacc[j][2]); pacc[j][2] = fmaf(w2.y,a.y,pacc[j][2]);
                        pacc[j][2] = fmaf(w2.z,a.z,pacc[j][2]); pacc[j][2] = fmaf(w2.w,a.w,pacc[j][2]);
                        pacc[j][3] = fmaf(w3.x,a.x,pacc[j][3]); pacc[j][3] = fmaf(w3.y,a.y,pacc[j][3]);
                        pacc[j][3] = fmaf(w3.z,a.z,pacc[j][3]); pacc[j][3] = fmaf(w3.w,a.w,pacc[j][3]);
                    }
                }
            }
            __syncthreads();                         // A reads done -> HA reusable
            #pragma unroll
            for (int j = 0; j < 8; ++j)
                P4p[(wv * 64 + blgrp + 8 * j) * 8 + uu] =
                    float4{pacc[j][0], pacc[j][1], pacc[j][2], pacc[j][3]};
            __syncthreads();                         // partials ready
            {
                const int r   = tid >> 2;            // token row 0..63
                const int up  = tid & 3;
                const int tl  = at * 2 + (r >> 5);
                const int bla = r & 31;
                float* dst = xz + ((size_t)blk * CH + tl) * 1024;
                #pragma unroll
                for (int q = 0; q < 2; ++q) {
                    const int uq = up + q * 4;
                    float4 s0 = P4p[(0 * 64 + r) * 8 + uq];
                    float4 s1 = P4p[(1 * 64 + r) * 8 + uq];
                    float4 s2 = P4p[(2 * 64 + r) * 8 + uq];
                    float4 s3 = P4p[(3 * 64 + r) * 8 + uq];
                    dst[(0 * 8 + uq) * 32 + bla] = s0.x + s1.x + s2.x + s3.x;
                    dst[(1 * 8 + uq) * 32 + bla] = s0.y + s1.y + s2.y + s3.y;
                    dst[(2 * 8 + uq) * 32 + bla] = s0.z + s1.z + s2.z + s3.z;
                    dst[(3 * 8 + uq) * 32 + bla] = s0.w + s1.w + s2.w + s3.w;
                }
            }
        }
        __syncthreads();

        // ============ scan CH steps ============
        for (int sc = 0; sc < CH; ++sc) {
            const int s   = ch * CH + sc;
            const int te  = dir ? (T_ - 1 - s) : s;
            const int cur = s & 1, nxt = cur ^ 1;

            // hoisted: barrier-independent loads (L2-warm)
            const int mtok = x[(b0base + bl) * T_ + te];
            float xzv[4];
            {
                const float* xzp = xz + ((size_t)blk * CH + sc) * 1024;
                #pragma unroll
                for (int g = 0; g < 4; ++g)
                    xzv[g] = xzp[(g * 8 + fuu) * 32 + bl] + bias4[g];
            }

            // wait: all 64 group members published h_s (relaxed; slots are
            // MALL-coherent; no L2 invalidation needed since h loads bypass L2)
            if (s > 0) {
                if (tid < 64) {
                    unsigned* slot = bar + (grp * 64 + tid) * 16;
                    while (__hip_atomic_load(slot, __ATOMIC_RELAXED,
                                             __HIP_MEMORY_SCOPE_AGENT) < (unsigned)s)
                        __builtin_amdgcn_s_sleep(1);
                }
                __syncthreads();
            }

            // stage h_s -> HA via agent-scope (L2-bypassing) loads + ds_write_b128
            {
                const char* hsrc = (const char*)(hbuf +
                    ((size_t)(cur * 2 + dir) * B_ + b0base) * U_);
                #pragma unroll
                for (int i = 0; i < 16; ++i) {
                    int off16 = (wv * 16 + i) * 64 + lane;   // float4 idx in 64KB
                    int row   = off16 >> 7;                  // 128 float4 per row
                    int col4  = off16 & 127;
                    const unsigned long long* p =
                        (const unsigned long long*)(hsrc + (size_t)off16 * 16);
                    unsigned long long a = __hip_atomic_load(p,     __ATOMIC_RELAXED,
                                                             __HIP_MEMORY_SCOPE_AGENT);
                    unsigned long long b = __hip_atomic_load(p + 1, __ATOMIC_RELAXED,
                                                             __HIP_MEMORY_SCOPE_AGENT);
                    float2 fa = __builtin_bit_cast(float2, a);
                    float2 fb = __builtin_bit_cast(float2, b);
                    HAw4[row * 129 + col4] = float4{fa.x, fa.y, fb.x, fb.y};
                }
            }
            __syncthreads();                         // h staged in LDS

            // partial z: this wave's k-slice, rows blgrp+8j, gates 0..3 (col uu)
            float pz[4][4];
            #pragma unroll
            for (int j = 0; j < 4; ++j)
                #pragma unroll
                for (int g = 0; g < 4; ++g) pz[j][g] = 0.0f;
            const int kbase = wv * 32;
            #pragma unroll 8
            for (int k4 = 0; k4 < 32; ++k4) {
                const int kk = kbase + k4;
                float4 h0 = HA4[(blgrp + 8 * 0) * 129 + kk];
                float4 h1 = HA4[(blgrp + 8 * 1) * 129 + kk];
                float4 h2 = HA4[(blgrp + 8 * 2) * 129 + kk];
                float4 h3 = HA4[(blgrp + 8 * 3) * 129 + kk];
                #pragma unroll
                for (int g = 0; g < 4; ++g) {
                    float4 w = Rl4[(g * 8 + uu) * 129 + kk];
                    pz[0][g] = fmaf(w.x,h0.x,pz[0][g]); pz[0][g] = fmaf(w.y,h0.y,pz[0][g]);
                    pz[0][g] = fmaf(w.z,h0.z,pz[0][g]); pz[0][g] = fmaf(w.w,h0.w,pz[0][g]);
                    pz[1][g] = fmaf(w.x,h1.x,pz[1][g]); pz[1][g] = fmaf(w.y,h1.y,pz[1][g]);
                    pz[1][g] = fmaf(w.z,h1.z,pz[1][g]); pz[1][g] = fmaf(w.w,h1.w,pz[1][g]);
                    pz[2][g] = fmaf(w.x,h2.x,pz[2][g]); pz[2][g] = fmaf(w.y,h2.y,pz[2][g]);
                    pz[2][g] = fmaf(w.z,h2.z,pz[2][g]); pz[2][g] = fmaf(w.w,h2.w,pz[2][g]);
                    pz[3][g] = fmaf(w.x,h3.x,pz[3][g]); pz[3][g] = fmaf(w.y,h3.y,pz[3][g]);
                    pz[3][g] = fmaf(w.z,h3.z,pz[3][g]); pz[3][g] = fmaf(w.w,h3.w,pz[3][g]);
                }
            }
            float h_old = HA[bl * RSTR + u0 + fuu];
            #pragma unroll
            for (int j = 0; j < 4; ++j)
                P4s[(wv * 32 + blgrp + 8 * j) * 8 + uu] =
                    float4{pz[j][0], pz[j][1], pz[j][2], pz[j][3]};
            __syncthreads();                         // partials ready

            float4 z0 = P4s[(0 * 32 + bl) * 8 + fuu];
            float4 z1 = P4s[(1 * 32 + bl) * 8 + fuu];
            float4 z2 = P4s[(2 * 32 + bl) * 8 + fuu];
            float4 z3 = P4s[(3 * 32 + bl) * 8 + fuu];
            float fi = tanhf(z0.x + z1.x + z2.x + z3.x + xzv[0]);
            float ff = tanhf(z0.y + z1.y + z2.y + z3.y + xzv[1]);
            float fg = tanhf(z0.z + z1.z + z2.z + z3.z + xzv[2]);
            float fo = tanhf(z0.w + z1.w + z2.w + z3.w + xzv[3]);
            float cn = fmaf(ff, c_reg, fi * fg);
            float hn = fo * tanhf(cn);
            bool  m  = (mtok != 0);
            float hsel = m ? hn : h_old;
            c_reg = m ? cn : c_reg;

            const int b = b0base + bl;
            __hip_atomic_store(&hbuf[((size_t)(nxt * 2 + dir) * B_ + b) * U_ + u0 + fuu],
                               hsel, __ATOMIC_RELAXED, __HIP_MEMORY_SCOPE_AGENT);
            out[((size_t)b * T_ + te) * 1024 + dir * 512 + u0 + fuu] = hsel;
            if (dir == 1 && s == T_ - 1)
                out[(size_t)B_ * T_ * 1024 + (size_t)b * U_ + u0 + fuu] = hsel;

            __syncthreads();       // vmcnt(0) drain: h write-through complete
            if (tid == 0)
                __hip_atomic_store(myslot, (unsigned)(s + 1), __ATOMIC_RELAXED,
                                   __HIP_MEMORY_SCOPE_AGENT);
        }
    }
}

extern "C" void kernel_launch(void* const* d_in, const int* in_sizes, int n_in,
                              void* d_out, int out_size, void* d_ws, size_t ws_size,
                              hipStream_t stream) {
    const int*   x   = (const int*)d_in[0];
    const float* emb = (const float*)d_in[1];
    const float* Wf  = (const float*)d_in[2];
    const float* Rf  = (const float*)d_in[3];
    const float* bfp = (const float*)d_in[4];
    const float* Wb  = (const float*)d_in[5];
    const float* Rb  = (const float*)d_in[6];
    const float* bbp = (const float*)d_in[7];
    float* out  = (float*)d_out;
    float* hbuf = (float*)d_ws;                                   // 512 KB
    unsigned* bar = (unsigned*)((char*)d_ws + 512 * 1024);        // 16 KB
    float* xzbuf  = (float*)((char*)d_ws + (1 << 20));            // CH MB

    int CH = 32;
    while (CH > 2 && (size_t)(CH + 1) * (1 << 20) > ws_size) CH >>= 1;

    hipMemsetAsync(hbuf, 0, (size_t)2 * B_ * U_ * sizeof(float), stream);
    hipMemsetAsync(bar, 0, 4 * 64 * 16 * sizeof(unsigned), stream);

    void* args[] = {
        (void*)&x, (void*)&emb,
        (void*)&Wf, (void*)&Rf, (void*)&bfp,
        (void*)&Wb, (void*)&Rb, (void*)&bbp,
        (void*)&out, (void*)&hbuf, (void*)&bar, (void*)&xzbuf, (void*)&CH
    };
    hipLaunchCooperativeKernel((const void*)bilstm_kernel,
                               dim3(256), dim3(256), args, 0, stream);
}

// Round 10
// 3380.258 us; speedup vs baseline: 4.0422x; 1.2761x over previous
//
#include <hip/hip_runtime.h>

#define V_ 32000
#define E_ 256
#define U_ 512
#define B_ 64
#define T_ 256
#define G_ 2048      // 4*U

#define RSTR 516     // R rows / scan-h rows: 512 data + 4 pad floats
#define ASTR 260     // precompute A rows: 256 data + 4 pad
#define WESTR 132    // We rows: 128 data + 4 pad

// d_ws layout:
//   [0, 512KB)   : hbuf float [2][2][B_][U_] (cur, dir, b, u)
//   [512KB, +16K): barrier slots, u32 at (grp*64+mem)*16 (64B stride)
//   [1MB, ...)   : xz chunk buffer [256 blk][CH][32 gc][32 b] floats
// Coherence (NO L2 invalidation anywhere):
//   h stores  : relaxed agent-scope atomic stores (write-through to MALL)
//   h loads   : relaxed agent-scope atomic loads (L2-bypassing, MALL-coherent)
//   slots     : relaxed agent-scope atomics, single-writer 64B-strided
// 512 threads = 8 waves: k-split 8 in both GEMMs; scan partial-reduce is
// two-phase (waves 4-7 write, waves 0-3 RMW) to fit the 16KB Wel buffer.

#define GLDS16(gsrc, ldst) __builtin_amdgcn_global_load_lds( \
    (const __attribute__((address_space(1))) void*)(gsrc),    \
    (__attribute__((address_space(3))) void*)(ldst), 16, 0, 0)

__global__ __launch_bounds__(512, 1)
void bilstm_kernel(const int* __restrict__ x,
                   const float* __restrict__ emb,
                   const float* __restrict__ Wf, const float* __restrict__ Rf,
                   const float* __restrict__ bf,
                   const float* __restrict__ Wb, const float* __restrict__ Rb,
                   const float* __restrict__ bb,
                   float* __restrict__ out, float* __restrict__ hbuf,
                   unsigned* __restrict__ bar, float* __restrict__ xz,
                   int CH)
{
    __shared__ __align__(16) float Rl[32 * RSTR];     // 66,048 B
    __shared__ __align__(16) float HA[64 * ASTR];     // 66,560 B (A / scan-h / pre-reduce)
    __shared__ __align__(16) float Wel[32 * WESTR];   // 16,896 B (W-half / scan-reduce)

    const int blk = blockIdx.x;
    const int dir = blk >> 7;
    const int rem = blk & 127;
    const int u0 = (rem >> 1) * 8;
    const int b0base = (rem & 1) * 32;
    const int grp = dir * 2 + (rem & 1);
    const int mem = rem >> 1;
    unsigned* myslot = bar + (grp * 64 + mem) * 16;

    const int tid   = threadIdx.x;       // 512
    const int wv    = tid >> 6;          // wave 0..7 (owns k-slice)
    const int lane  = tid & 63;
    const int uu    = lane & 7;          // gate-col sub-index
    const int blgrp = lane >> 3;         // 0..7
    const int blf   = tid >> 3;          // finalize mapping (valid tid<256): batch 0..31
    const int fuu   = tid & 7;           // finalize mapping: u sub-index

    const float* Wd = dir ? Wb : Wf;
    const float* Rd = dir ? Rb : Rf;
    const float* bd = dir ? bb : bf;

    // ---- one-time: stage R transposed into LDS ----
    {
        const int sgc  = tid & 31;
        const int gcol = ((sgc >> 3) * 512) + u0 + (sgc & 7);
        for (int k = tid >> 5; k < 512; k += 16)
            Rl[sgc * RSTR + k] = Rd[(size_t)k * G_ + gcol];
    }
    float bias4[4];
    #pragma unroll
    for (int g = 0; g < 4; ++g) bias4[g] = bd[g * 512 + u0 + fuu];

    float c_reg = 0.0f;
    const float4* Rl4  = reinterpret_cast<const float4*>(Rl);
    const float4* HA4  = reinterpret_cast<const float4*>(HA);
    const float4* Wel4 = reinterpret_cast<const float4*>(Wel);
    float4* HAw4 = reinterpret_cast<float4*>(HA);   // staging writes
    float4* P4s = reinterpret_cast<float4*>(Wel);   // scan reduce buffer (16 KB)
    float4* P4p = reinterpret_cast<float4*>(HA);    // precompute reduce buffer (64 KB)

    __syncthreads();

    const int nch = T_ / CH;
    for (int ch = 0; ch < nch; ++ch) {
        // ============ precompute xz = e@W for this chunk (k-split-8 GEMM) ============
        const int nat = CH >> 1;                     // A-tiles of 2t x 32b
        for (int at = 0; at < nat; ++at) {
            __syncthreads();                         // HA & Wel free
            // stage A: 64 rows x 1KB
            for (int i = 0; i < 8; ++i) {
                int rr   = wv * 8 + i;
                int tloc = at * 2 + (rr >> 5);
                int bla  = rr & 31;
                int sg   = ch * CH + tloc;
                int tea  = dir ? (T_ - 1 - sg) : sg;
                int tok  = x[(b0base + bla) * T_ + tea];
                GLDS16(emb + (size_t)tok * E_ + lane * 4, HA + rr * ASTR);
            }
            float pacc[8][4];
            #pragma unroll
            for (int j = 0; j < 8; ++j)
                #pragma unroll
                for (int g = 0; g < 4; ++g) pacc[j][g] = 0.0f;

            for (int kh = 0; kh < 2; ++kh) {
                if (kh) __syncthreads();             // Wel half-0 reads done
                {
                    const int sgc  = tid & 31;
                    const int gcol = ((sgc >> 3) * 512) + u0 + (sgc & 7);
                    for (int kk = tid >> 5; kk < 128; kk += 16)
                        Wel[sgc * WESTR + kk] = Wd[(size_t)(kh * 128 + kk) * G_ + gcol];
                }
                __syncthreads();                     // A (vmcnt drained) + Wel ready
                #pragma unroll
                for (int k4 = 0; k4 < 4; ++k4) {
                    const int kw = wv * 4 + k4;      // k4-index within half (0..31)
                    float4 w0 = Wel4[(0 * 8 + uu) * 33 + kw];
                    float4 w1 = Wel4[(1 * 8 + uu) * 33 + kw];
                    float4 w2 = Wel4[(2 * 8 + uu) * 33 + kw];
                    float4 w3 = Wel4[(3 * 8 + uu) * 33 + kw];
                    #pragma unroll
                    for (int j = 0; j < 8; ++j) {
                        float4 a = HA4[(blgrp + 8 * j) * 65 + kh * 32 + kw];
                        pacc[j][0] = fmaf(w0.x,a.x,pacc[j][0]); pacc[j][0] = fmaf(w0.y,a.y,pacc[j][0]);
                        pacc[j][0] = fmaf(w0.z,a.z,pacc[j][0]); pacc[j][0] = fmaf(w0.w,a.w,pacc[j][0]);
                        pacc[j][1] = fmaf(w1.x,a.x,pacc[j][1]); pacc[j][1] = fmaf(w1.y,a.y,pacc[j][1]);
                        pacc[j][1] = fmaf(w1.z,a.z,pacc[j][1]); pacc[j][1] = fmaf(w1.w,a.w,pacc[j][1]);
                        pacc[j][2] = fmaf(w2.x,a.x,pacc[j][2]); pacc[j][2] = fmaf(w2.y,a.y,pacc[j][2]);
                        pacc[j][2] = fmaf(w2.z,a.z,pacc[j][2]); pacc[j][2] = fmaf(w2.w,a.w,pacc[j][2]);
                        pacc[j][3] = fmaf(w3.x,a.x,pacc[j][3]); pacc[j][3] = fmaf(w3.y,a.y,pacc[j][3]);
                        pacc[j][3] = fmaf(w3.z,a.z,pacc[j][3]); pacc[j][3] = fmaf(w3.w,a.w,pacc[j][3]);
                    }
                }
            }
            __syncthreads();                         // A reads done -> HA reusable
            #pragma unroll
            for (int j = 0; j < 8; ++j)
                P4p[(wv * 64 + blgrp + 8 * j) * 8 + uu] =
                    float4{pacc[j][0], pacc[j][1], pacc[j][2], pacc[j][3]};
            __syncthreads();                         // partials ready
            {
                const int r   = tid >> 3;            // token row 0..63
                const int uq  = tid & 7;
                const int tl  = at * 2 + (r >> 5);
                const int bla = r & 31;
                float* dst = xz + ((size_t)blk * CH + tl) * 1024;
                float4 s = P4p[(0 * 64 + r) * 8 + uq];
                #pragma unroll
                for (int q = 1; q < 8; ++q) {
                    float4 p = P4p[(q * 64 + r) * 8 + uq];
                    s.x += p.x; s.y += p.y; s.z += p.z; s.w += p.w;
                }
                dst[(0 * 8 + uq) * 32 + bla] = s.x;
                dst[(1 * 8 + uq) * 32 + bla] = s.y;
                dst[(2 * 8 + uq) * 32 + bla] = s.z;
                dst[(3 * 8 + uq) * 32 + bla] = s.w;
            }
        }
        __syncthreads();

        // ============ scan CH steps ============
        for (int sc = 0; sc < CH; ++sc) {
            const int s   = ch * CH + sc;
            const int te  = dir ? (T_ - 1 - s) : s;
            const int cur = s & 1, nxt = cur ^ 1;

            // hoisted: barrier-independent loads (finalize threads only)
            int mtok = 0;
            float xzv[4] = {0.f, 0.f, 0.f, 0.f};
            if (tid < 256) {
                mtok = x[(b0base + blf) * T_ + te];
                const float* xzp = xz + ((size_t)blk * CH + sc) * 1024;
                #pragma unroll
                for (int g = 0; g < 4; ++g)
                    xzv[g] = xzp[(g * 8 + fuu) * 32 + blf] + bias4[g];
            }

            // wait: all 64 group members published h_s
            if (s > 0) {
                if (tid < 64) {
                    unsigned* slot = bar + (grp * 64 + tid) * 16;
                    while (__hip_atomic_load(slot, __ATOMIC_RELAXED,
                                             __HIP_MEMORY_SCOPE_AGENT) < (unsigned)s)
                        __builtin_amdgcn_s_sleep(1);
                }
                __syncthreads();
            }

            // stage h_s -> HA via agent-scope (L2-bypassing) loads + ds_write_b128
            {
                const char* hsrc = (const char*)(hbuf +
                    ((size_t)(cur * 2 + dir) * B_ + b0base) * U_);
                #pragma unroll
                for (int i = 0; i < 8; ++i) {
                    int off16 = (wv * 8 + i) * 64 + lane;    // float4 idx in 64KB
                    int row   = off16 >> 7;                  // 128 float4 per row
                    int col4  = off16 & 127;
                    const unsigned long long* p =
                        (const unsigned long long*)(hsrc + (size_t)off16 * 16);
                    unsigned long long a = __hip_atomic_load(p,     __ATOMIC_RELAXED,
                                                             __HIP_MEMORY_SCOPE_AGENT);
                    unsigned long long b = __hip_atomic_load(p + 1, __ATOMIC_RELAXED,
                                                             __HIP_MEMORY_SCOPE_AGENT);
                    float2 fa = __builtin_bit_cast(float2, a);
                    float2 fb = __builtin_bit_cast(float2, b);
                    HAw4[row * 129 + col4] = float4{fa.x, fa.y, fb.x, fb.y};
                }
            }
            __syncthreads();                         // h staged in LDS

            // partial z: this wave's 64-k slice, rows blgrp+8j, cols g*8+uu
            float pz[4][4];
            #pragma unroll
            for (int j = 0; j < 4; ++j)
                #pragma unroll
                for (int g = 0; g < 4; ++g) pz[j][g] = 0.0f;
            const int kbase = wv * 16;
            #pragma unroll 4
            for (int k4 = 0; k4 < 16; ++k4) {
                const int kk = kbase + k4;
                float4 h0 = HA4[(blgrp + 8 * 0) * 129 + kk];
                float4 h1 = HA4[(blgrp + 8 * 1) * 129 + kk];
                float4 h2 = HA4[(blgrp + 8 * 2) * 129 + kk];
                float4 h3 = HA4[(blgrp + 8 * 3) * 129 + kk];
                #pragma unroll
                for (int g = 0; g < 4; ++g) {
                    float4 w = Rl4[(g * 8 + uu) * 129 + kk];
                    pz[0][g] = fmaf(w.x,h0.x,pz[0][g]); pz[0][g] = fmaf(w.y,h0.y,pz[0][g]);
                    pz[0][g] = fmaf(w.z,h0.z,pz[0][g]); pz[0][g] = fmaf(w.w,h0.w,pz[0][g]);
                    pz[1][g] = fmaf(w.x,h1.x,pz[1][g]); pz[1][g] = fmaf(w.y,h1.y,pz[1][g]);
                    pz[1][g] = fmaf(w.z,h1.z,pz[1][g]); pz[1][g] = fmaf(w.w,h1.w,pz[1][g]);
                    pz[2][g] = fmaf(w.x,h2.x,pz[2][g]); pz[2][g] = fmaf(w.y,h2.y,pz[2][g]);
                    pz[2][g] = fmaf(w.z,h2.z,pz[2][g]); pz[2][g] = fmaf(w.w,h2.w,pz[2][g]);
                    pz[3][g] = fmaf(w.x,h3.x,pz[3][g]); pz[3][g] = fmaf(w.y,h3.y,pz[3][g]);
                    pz[3][g] = fmaf(w.z,h3.z,pz[3][g]); pz[3][g] = fmaf(w.w,h3.w,pz[3][g]);
                }
            }
            float h_old = (tid < 256) ? HA[blf * RSTR + u0 + fuu] : 0.0f;

            // two-phase k-reduce into 16KB P4s: waves 4-7 write, waves 0-3 RMW
            if (wv >= 4) {
                #pragma unroll
                for (int j = 0; j < 4; ++j)
                    P4s[((wv - 4) * 32 + blgrp + 8 * j) * 8 + uu] =
                        float4{pz[j][0], pz[j][1], pz[j][2], pz[j][3]};
            }
            __syncthreads();
            if (wv < 4) {
                #pragma unroll
                for (int j = 0; j < 4; ++j) {
                    const int idx = (wv * 32 + blgrp + 8 * j) * 8 + uu;
                    float4 t = P4s[idx];
                    t.x += pz[j][0]; t.y += pz[j][1];
                    t.z += pz[j][2]; t.w += pz[j][3];
                    P4s[idx] = t;
                }
            }
            __syncthreads();                         // partials ready

            if (tid < 256) {
                float4 z0 = P4s[(0 * 32 + blf) * 8 + fuu];
                float4 z1 = P4s[(1 * 32 + blf) * 8 + fuu];
                float4 z2 = P4s[(2 * 32 + blf) * 8 + fuu];
                float4 z3 = P4s[(3 * 32 + blf) * 8 + fuu];
                float fi = tanhf(z0.x + z1.x + z2.x + z3.x + xzv[0]);
                float ff = tanhf(z0.y + z1.y + z2.y + z3.y + xzv[1]);
                float fg = tanhf(z0.z + z1.z + z2.z + z3.z + xzv[2]);
                float fo = tanhf(z0.w + z1.w + z2.w + z3.w + xzv[3]);
                float cn = fmaf(ff, c_reg, fi * fg);
                float hn = fo * tanhf(cn);
                bool  m  = (mtok != 0);
                float hsel = m ? hn : h_old;
                c_reg = m ? cn : c_reg;

                const int b = b0base + blf;
                __hip_atomic_store(&hbuf[((size_t)(nxt * 2 + dir) * B_ + b) * U_ + u0 + fuu],
                                   hsel, __ATOMIC_RELAXED, __HIP_MEMORY_SCOPE_AGENT);
                out[((size_t)b * T_ + te) * 1024 + dir * 512 + u0 + fuu] = hsel;
                if (dir == 1 && s == T_ - 1)
                    out[(size_t)B_ * T_ * 1024 + (size_t)b * U_ + u0 + fuu] = hsel;
            }

            __syncthreads();       // vmcnt(0) drain: h write-through complete
            if (tid == 0)
                __hip_atomic_store(myslot, (unsigned)(s + 1), __ATOMIC_RELAXED,
                                   __HIP_MEMORY_SCOPE_AGENT);
        }
    }
}

extern "C" void kernel_launch(void* const* d_in, const int* in_sizes, int n_in,
                              void* d_out, int out_size, void* d_ws, size_t ws_size,
                              hipStream_t stream) {
    const int*   x   = (const int*)d_in[0];
    const float* emb = (const float*)d_in[1];
    const float* Wf  = (const float*)d_in[2];
    const float* Rf  = (const float*)d_in[3];
    const float* bfp = (const float*)d_in[4];
    const float* Wb  = (const float*)d_in[5];
    const float* Rb  = (const float*)d_in[6];
    const float* bbp = (const float*)d_in[7];
    float* out  = (float*)d_out;
    float* hbuf = (float*)d_ws;                                   // 512 KB
    unsigned* bar = (unsigned*)((char*)d_ws + 512 * 1024);        // 16 KB
    float* xzbuf  = (float*)((char*)d_ws + (1 << 20));            // CH MB

    int CH = 32;
    while (CH > 2 && (size_t)(CH + 1) * (1 << 20) > ws_size) CH >>= 1;

    hipMemsetAsync(hbuf, 0, (size_t)2 * B_ * U_ * sizeof(float), stream);
    hipMemsetAsync(bar, 0, 4 * 64 * 16 * sizeof(unsigned), stream);

    void* args[] = {
        (void*)&x, (void*)&emb,
        (void*)&Wf, (void*)&Rf, (void*)&bfp,
        (void*)&Wb, (void*)&Rb, (void*)&bbp,
        (void*)&out, (void*)&hbuf, (void*)&bar, (void*)&xzbuf, (void*)&CH
    };
    hipLaunchCooperativeKernel((const void*)bilstm_kernel,
                               dim3(256), dim3(512), args, 0, stream);
}